// Round 5
// baseline (188.949 us; speedup 1.0000x reference)
//
#include <hip/hip_runtime.h>

// MultiHeadAttention: B=2,S=2048,D=1024,H=16,dh=64. fp32 in/out, bf16 MFMA internally.
// R12: gemm_qkv ported to the 256^2 8-phase counted-vmcnt template (T3+T4+T5):
//  - 512 thr / 8 waves (2Mx4N), per-wave 128x64 output, acc[8][4] f32x4.
//  - LDS 128KB: A,B each [2 buf][256x64] bf16, XOR-swizzled (T2, carried over).
//  - per K-tile (BK=64): 4 phases {ds-read subtile; issue 1 half-tile gl_lds; 16 MFMA
//    (setprio-wrapped)}, one s_barrier between phases.
//  - counted vmcnt at K-tile top ONLY: vmcnt(4) (2 half-tiles in flight across
//    barriers), vmcnt(0) only before the last K-tile. Staging ledger: ph0/ph1 stage
//    A-halves of kt+1 (A buf freed at prev tile's ph2), ph2/ph3 stage B-halves of
//    kt+2 (B buf freed at this tile's ph1).
//  - grid 192 (16 rows x 12 cols), 1 block/CU, no tail.
// prep/attn/gemm_proj unchanged from R11 (controls).

typedef __attribute__((ext_vector_type(8))) short short8;
typedef __attribute__((ext_vector_type(4))) float f32x4;

#define MFMA_B16(a, b, c) __builtin_amdgcn_mfma_f32_16x16x32_bf16(a, b, c, 0, 0, 0)

#if __has_builtin(__builtin_amdgcn_exp2f)
#define EXP2(x) __builtin_amdgcn_exp2f(x)
#else
#define EXP2(x) exp2f(x)
#endif

static __device__ __forceinline__ unsigned short f2bf(float f) {
    union { float f; unsigned int u; } v;
    v.f = f;
    unsigned int r = (v.u + 0x7fffu + ((v.u >> 16) & 1u)) >> 16;
    return (unsigned short)r;
}

static __device__ __forceinline__ unsigned int pk_bf16(float a, float b) {
#if __has_builtin(__builtin_amdgcn_cvt_pk_bf16_f32)
    typedef __bf16 bf2 __attribute__((ext_vector_type(2)));
    union { bf2 v; unsigned int u; } c;
    c.v = __builtin_amdgcn_cvt_pk_bf16_f32(a, b);
    return c.u;
#else
    return (unsigned int)f2bf(a) | ((unsigned int)f2bf(b) << 16);
#endif
}

static __device__ __forceinline__ void gl_lds16(const void* g, void* l) {
    __builtin_amdgcn_global_load_lds(
        (const __attribute__((address_space(1))) unsigned int*)g,
        (__attribute__((address_space(3))) unsigned int*)l, 16, 0, 0);
}

// ---------------- fused prep: convert x + transpose both weights ----------------
__global__ __launch_bounds__(256) void prep_kernel(const float4* __restrict__ x,
                                                   uint4* __restrict__ xb,
                                                   const float* __restrict__ wqkv,
                                                   unsigned short* __restrict__ wqkvT,
                                                   const float* __restrict__ wproj,
                                                   unsigned short* __restrict__ wprojT) {
    const int bid = blockIdx.x;
    if (bid < 2048) {
        int i = bid * 256 + threadIdx.x;   // 0..524287, 8 floats each
        float4 v0 = x[i * 2], v1 = x[i * 2 + 1];
        uint4 o;
        o.x = pk_bf16(v0.x, v0.y);
        o.y = pk_bf16(v0.z, v0.w);
        o.z = pk_bf16(v1.x, v1.y);
        o.w = pk_bf16(v1.z, v1.w);
        xb[i] = o;
        return;
    }
    __shared__ float t[32][33];
    const float* in;
    unsigned short* out;
    int R, C, bx, by;
    if (bid < 2048 + 3072) {
        int g = bid - 2048;
        in = wqkv; out = wqkvT; R = 1024; C = 3072;
        bx = g % 96; by = g / 96;
    } else {
        int g = bid - 5120;
        in = wproj; out = wprojT; R = 1024; C = 1024;
        bx = g & 31; by = g >> 5;
    }
    const int c0 = bx * 32, r0 = by * 32;
    const int xx = threadIdx.x & 31, yy0 = threadIdx.x >> 5;
    #pragma unroll
    for (int yy = yy0; yy < 32; yy += 8)
        t[yy][xx] = in[(size_t)(r0 + yy) * C + (c0 + xx)];
    __syncthreads();
    #pragma unroll
    for (int yy = yy0; yy < 32; yy += 8)
        out[(size_t)(c0 + yy) * R + (r0 + xx)] = f2bf(t[xx][yy]);
}

// ---------------- QKV GEMM: C[4096x3072] = A * Bt^T (R12 8-phase 256^2) ----------------
// grid 192: colblk = bid>>4 (0..11), rowblk = bid&15. col0 = colblk*256 stays within one
// of Q (cols 0-1023), K (1024-2047), V (2048-3071). Q/K: swapped MFMA (C^T). V: unswapped,
// direct stores to vT [bh][d][s].
__global__ __launch_bounds__(512) void gemm_qkv_kernel(const unsigned short* __restrict__ A,
                                                       const unsigned short* __restrict__ Bt,
                                                       const float* __restrict__ bias,
                                                       unsigned short* __restrict__ q,
                                                       unsigned short* __restrict__ k,
                                                       unsigned short* __restrict__ vT) {
    __shared__ unsigned short As[2][16384];   // [buf][256 rows x 64 cols]
    __shared__ unsigned short Bs[2][16384];
    const int tid = threadIdx.x;
    const int lane = tid & 63;
    const int wave = tid >> 6;
    const int l15 = lane & 15, quad = lane >> 4;
    const int wm = wave >> 2, wn = wave & 3;       // 2M x 4N waves
    const int bid = blockIdx.x;
    const int colblk = bid >> 4, rowblk = bid & 15;
    const int row0 = rowblk * 256, col0 = colblk * 256;
    const int K = 1024;
    const int sel = col0 >> 10;                    // 0=Q, 1=K, 2=V
    const bool isV = (sel == 2);

    // staging: per half-tile (128 rows x 64 cols bf16 = 16KB), 2 rounds of 512thr x 16B
    const int sr = tid >> 3;      // base row within round
    const int c8 = tid & 7;       // column chunk

    auto stageA = [&](int buf, int h, int kt) {
        #pragma unroll
        for (int g = 0; g < 2; ++g) {
            const int r = g * 64 + sr;
            const int cs = c8 ^ (r & 7);
            gl_lds16(&A[(size_t)(row0 + h * 128 + r) * K + kt * 64 + cs * 8],
                     &As[buf][h * 8192 + g * 4096 + tid * 8]);
        }
    };
    auto stageB = [&](int buf, int h, int kt) {
        #pragma unroll
        for (int g = 0; g < 2; ++g) {
            const int r = g * 64 + sr;
            const int cs = c8 ^ (r & 7);
            gl_lds16(&Bt[(size_t)(col0 + h * 128 + r) * K + kt * 64 + cs * 8],
                     &Bs[buf][h * 8192 + g * 4096 + tid * 8]);
        }
    };

    f32x4 acc[8][4] = {};

    // prologue (issue order matters for vmcnt ledger):
    // Bh0(0) Bh1(0) Ah0(0) Ah1(0) Bh0(1) Bh1(1)  -> 12 loads/thread
    stageB(0, 0, 0); stageB(0, 1, 0);
    stageA(0, 0, 0); stageA(0, 1, 0);
    stageB(1, 0, 1); stageB(1, 1, 1);

#define LOAD_AF(IBASE)                                                                   \
    _Pragma("unroll") for (int i = 0; i < 4; ++i) {                                      \
        const int r = wm * 128 + ((IBASE) + i) * 16 + l15;                               \
        _Pragma("unroll") for (int kk = 0; kk < 2; ++kk)                                 \
            afr[i][kk] = *(const short8*)&Ac[r * 64 + (((kk * 4 + quad) ^ (r & 7)) * 8)];\
    }
#define LOAD_BF(JBASE)                                                                   \
    _Pragma("unroll") for (int j = 0; j < 2; ++j) {                                      \
        const int r = wn * 64 + ((JBASE) + j) * 16 + l15;                                 \
        _Pragma("unroll") for (int kk = 0; kk < 2; ++kk)                                 \
            bfr[(JBASE) + j][kk] =                                                       \
                *(const short8*)&Bc[r * 64 + (((kk * 4 + quad) ^ (r & 7)) * 8)];         \
    }
#define MFMA_SET(ILO, JLO)                                                               \
    __builtin_amdgcn_s_setprio(1);                                                       \
    if (isV) {                                                                           \
        _Pragma("unroll") for (int i = 0; i < 4; ++i)                                    \
        _Pragma("unroll") for (int j = 0; j < 2; ++j) {                                  \
            acc[(ILO) + i][(JLO) + j] =                                                  \
                MFMA_B16(afr[i][0], bfr[(JLO) + j][0], acc[(ILO) + i][(JLO) + j]);       \
            acc[(ILO) + i][(JLO) + j] =                                                  \
                MFMA_B16(afr[i][1], bfr[(JLO) + j][1], acc[(ILO) + i][(JLO) + j]);       \
        }                                                                                \
    } else {                                                                             \
        _Pragma("unroll") for (int i = 0; i < 4; ++i)                                    \
        _Pragma("unroll") for (int j = 0; j < 2; ++j) {                                  \
            acc[(ILO) + i][(JLO) + j] =                                                  \
                MFMA_B16(bfr[(JLO) + j][0], afr[i][0], acc[(ILO) + i][(JLO) + j]);       \
            acc[(ILO) + i][(JLO) + j] =                                                  \
                MFMA_B16(bfr[(JLO) + j][1], afr[i][1], acc[(ILO) + i][(JLO) + j]);       \
        }                                                                                \
    }                                                                                    \
    __builtin_amdgcn_s_setprio(0);

    for (int kt = 0; kt < 16; ++kt) {
        const int cur = kt & 1;
        // K-tile top: counted wait. Newest 4 loads (= B halves of kt+1) stay in flight;
        // everything tile kt needs is forced complete. Last tile: drain.
        if (kt == 15) {
            asm volatile("s_waitcnt vmcnt(0)" ::: "memory");
        } else {
            asm volatile("s_waitcnt vmcnt(4)" ::: "memory");
        }
        __builtin_amdgcn_s_barrier();
        __builtin_amdgcn_sched_barrier(0);   // keep tile-kt LDS reads below the barrier

        const unsigned short* Ac = As[cur];
        const unsigned short* Bc = Bs[cur];

        short8 afr[4][2], bfr[4][2];

        // ph0: reads af[0..3], bf[0..1]; stage Ah0(kt+1); MFMA (i0-3 x j0-1)
        LOAD_AF(0)
        LOAD_BF(0)
        if (kt + 1 < 16) stageA(cur ^ 1, 0, kt + 1);
        MFMA_SET(0, 0)
        __builtin_amdgcn_s_barrier();

        // ph1: reads bf[2..3]; stage Ah1(kt+1); MFMA (i0-3 x j2-3)
        LOAD_BF(2)
        if (kt + 1 < 16) stageA(cur ^ 1, 1, kt + 1);
        MFMA_SET(0, 2)
        __builtin_amdgcn_s_barrier();

        // ph2: reads af[4..7]; stage Bh0(kt+2) into freed B buf; MFMA (i4-7 x j2-3)
        LOAD_AF(4)
        if (kt + 2 < 16) stageB(cur, 0, kt + 2);
        MFMA_SET(4, 2)
        __builtin_amdgcn_s_barrier();

        // ph3: no reads (bf[0..1] still in regs); stage Bh1(kt+2); MFMA (i4-7 x j0-1)
        if (kt + 2 < 16) stageB(cur, 1, kt + 2);
        MFMA_SET(4, 0)
        // next K-tile-top barrier closes this phase
    }

#undef LOAD_AF
#undef LOAD_BF
#undef MFMA_SET

    const int b = row0 >> 11;
    const int s0 = row0 & 2047;
    const int hh = ((col0 & 1023) >> 6) + wn;      // this wave's head
    const float* bb = bias + col0 + wn * 64;

    if (!isV) {
        // C^T: lane holds d = j*16 + quad*4 + {0..3} for s = wm*128 + i*16 + l15
        unsigned short* dst = (sel == 1) ? k : q;
        const float scale = (sel == 1) ? 1.0f : 0.1803368867f;  // 1/8 * log2(e) for Q
        #pragma unroll
        for (int i = 0; i < 8; ++i) {
            const int s = s0 + wm * 128 + i * 16 + l15;
            unsigned short* drow = dst + ((size_t)((b * 16 + hh) * 2048 + s)) * 64;
            #pragma unroll
            for (int j = 0; j < 4; ++j) {
                float4 b4 = ((const float4*)bb)[j * 4 + quad];
                uint2 pv;
                pv.x = pk_bf16((acc[i][j][0] + b4.x) * scale, (acc[i][j][1] + b4.y) * scale);
                pv.y = pk_bf16((acc[i][j][2] + b4.z) * scale, (acc[i][j][3] + b4.w) * scale);
                *(uint2*)&drow[j * 16 + quad * 4] = pv;
            }
        }
    } else {
        // C: lane holds s = wm*128 + i*16 + quad*4 + {0..3} for d = j*16 + l15
        #pragma unroll
        for (int j = 0; j < 4; ++j) {
            const int d = j * 16 + l15;
            const float bv = bb[d];
            unsigned short* drow = vT + ((size_t)((b * 16 + hh) * 64 + d)) * 2048 + s0;
            #pragma unroll
            for (int i = 0; i < 8; ++i) {
                uint2 pv;
                pv.x = pk_bf16(acc[i][j][0] + bv, acc[i][j][1] + bv);
                pv.y = pk_bf16(acc[i][j][2] + bv, acc[i][j][3] + bv);
                *(uint2*)&drow[wm * 128 + i * 16 + quad * 4] = pv;
            }
        }
    }
}

// ---------------- proj GEMM: out[4096x1024] fp32 = A * Bt^T + bias ----------------
// 1-D grid 512, XCD-grouped (2 cols per XCD). R11 dbuf + single barrier per K-step.
__global__ __launch_bounds__(256) void gemm_proj_kernel(const unsigned short* __restrict__ A,
                                                        const unsigned short* __restrict__ Bt,
                                                        const float* __restrict__ bias,
                                                        float* __restrict__ out) {
    __shared__ unsigned short As[2][8192];
    __shared__ unsigned short Bs[2][4096];
    const int tid = threadIdx.x;
    const int lane = tid & 63, wave = tid >> 6;
    const int l15 = lane & 15, quad = lane >> 4;
    const int wm = wave >> 1, wn = wave & 1;
    const int bid = blockIdx.x;
    const int xcd = bid & 7, jj = bid >> 3;       // jj 0..63
    const int colb = xcd * 2 + (jj & 1);          // 0..15
    const int row0 = (jj >> 1) * 128, col0 = colb * 64;
    const int K = 1024;

    int srow[4], scol[4], sdst[4];
    #pragma unroll
    for (int h = 0; h < 4; ++h) {
        int D = h * 256 + wave * 64 + lane;
        srow[h] = D >> 3;
        scol[h] = ((D & 7) ^ (srow[h] & 7)) * 8;
        sdst[h] = (h * 256 + wave * 64) * 8;
    }

    f32x4 acc[4][2] = {};

    // prologue: stage K-tile 0 into buf 0
    #pragma unroll
    for (int h = 0; h < 4; ++h)
        gl_lds16(&A[(size_t)(row0 + srow[h]) * K + scol[h]], &As[0][sdst[h]]);
    #pragma unroll
    for (int h = 0; h < 2; ++h)
        gl_lds16(&Bt[(size_t)(col0 + srow[h]) * K + scol[h]], &Bs[0][sdst[h]]);
    __syncthreads();

    for (int kt = 0; kt < 16; ++kt) {
        const int cur = kt & 1;
        if (kt + 1 < 16) {
            const int ko = (kt + 1) * 64;
            #pragma unroll
            for (int h = 0; h < 4; ++h)
                gl_lds16(&A[(size_t)(row0 + srow[h]) * K + ko + scol[h]], &As[cur ^ 1][sdst[h]]);
            #pragma unroll
            for (int h = 0; h < 2; ++h)
                gl_lds16(&Bt[(size_t)(col0 + srow[h]) * K + ko + scol[h]], &Bs[cur ^ 1][sdst[h]]);
        }
        #pragma unroll
        for (int kk = 0; kk < 2; ++kk) {
            short8 af[4], bf[2];
            #pragma unroll
            for (int i = 0; i < 4; ++i) {
                int r = wm * 64 + i * 16 + l15;
                af[i] = *(const short8*)&As[cur][r * 64 + (((kk * 4 + quad) ^ (r & 7)) * 8)];
            }
            #pragma unroll
            for (int j = 0; j < 2; ++j) {
                int r = wn * 32 + j * 16 + l15;
                bf[j] = *(const short8*)&Bs[cur][r * 64 + (((kk * 4 + quad) ^ (r & 7)) * 8)];
            }
            #pragma unroll
            for (int i = 0; i < 4; ++i)
                #pragma unroll
                for (int j = 0; j < 2; ++j)
                    acc[i][j] = MFMA_B16(bf[j], af[i], acc[i][j]);  // C^T
        }
        __syncthreads();
    }

    const float* bb = bias + col0 + wn * 32;
    #pragma unroll
    for (int i = 0; i < 4; ++i) {
        const int row = row0 + wm * 64 + i * 16 + l15;
        #pragma unroll
        for (int j = 0; j < 2; ++j) {
            float4 b4 = ((const float4*)bb)[j * 4 + quad];
            float4 ov;
            ov.x = acc[i][j][0] + b4.x;
            ov.y = acc[i][j][1] + b4.y;
            ov.z = acc[i][j][2] + b4.z;
            ov.w = acc[i][j][3] + b4.w;
            *(float4*)&out[(size_t)row * 1024 + col0 + wn * 32 + j * 16 + quad * 4] = ov;
        }
    }
}

// ---------------- flash attention (R10: adjacent-pair 512-thread blocks) ----------------
// smem layout (shorts): [0..4095] Ks0 | [4096..8191] Ks1 | [8192..12287] Vs0
//                       [12288..16383] Vs1 | [16384..24575] Pw[8][1024]
__global__ __launch_bounds__(512) void attn_kernel(const unsigned short* __restrict__ Q,
                                                   const unsigned short* __restrict__ Kg,
                                                   const unsigned short* __restrict__ Vt,
                                                   const int* __restrict__ idx,
                                                   const float* __restrict__ weight,
                                                   const int* __restrict__ forcing,
                                                   unsigned short* __restrict__ O) {
    __shared__ unsigned short smem[24576];

    const int tid = threadIdx.x;
    const int lane = tid & 63, wave = tid >> 6;
    const int l15 = lane & 15, quad = lane >> 4;
    const int bid = blockIdx.x;
    const int qh = bid >> 8;          // 0 = long half, 1 = short half
    const int rem = bid & 255;
    const int xcd = rem & 7;
    const int head = (rem >> 3) & 3;
    const int g2 = rem >> 5;          // 0..7
    const int p = qh ? (7 - g2) : (8 + g2);
    const int bh = xcd * 4 + head;
    const int tA = 2 * p + 1, tB = 2 * p;  // adjacent q-tiles
    const int b = bh >> 4, hh = bh & 15;
    const unsigned short* Qb = Q + (size_t)bh * 2048 * 64;
    const unsigned short* Kh = Kg + (size_t)bh * 2048 * 64;
    const unsigned short* Vh = Vt + (size_t)bh * 2048 * 64;

    const int idxb = idx[b];
    const float lw = (forcing[0] != 0) ? __log2f(weight[0]) : 0.0f;

    // this wave's q-tile: waves 0-3 -> tA, waves 4-7 -> tB (idle only on last tile)
    const int wq = (wave < 4) ? tA : tB;
    const int wg = wave & 3;
    const int q0 = wq * 64 + wg * 16;
    const int qrow = q0 + l15;
    const int nkb = tA + 1;    // block-level k-tile count (= 2p+2)
    const int nkbw = wq + 1;   // this wave's active k-tile count

    // staging: 512 threads, 1 K-chunk + 1 V-chunk (16B) each per tile
    const int rS = tid >> 3;
    const int cS8 = ((tid & 7) ^ (rS & 7)) * 8;

    short8 aq0 = *(const short8*)&Qb[(q0 + l15) * 64 + quad * 8];
    short8 aq1 = *(const short8*)&Qb[(q0 + l15) * 64 + 32 + quad * 8];

    const short8 ones8 = {0x3F80, 0x3F80, 0x3F80, 0x3F80, 0x3F80, 0x3F80, 0x3F80, 0x3F80};

    f32x4 o[4] = {};
    f32x4 lsum = {};

    // prologue: stage tile 0
    gl_lds16(Kh + (size_t)rS * 64 + cS8,   &smem[tid * 8]);
    gl_lds16(Vh + (size_t)rS * 2048 + cS8, &smem[8192 + tid * 8]);
    __syncthreads();

    unsigned short* const pwb = &smem[16384 + wave * 1024];
    const int pwr = l15 * 64;
    const int pa7 = l15 & 7;

    for (int kb = 0; kb < nkb; ++kb) {
        const int cur = kb & 1;
        const int kbase = kb * 64;
        if (kb + 1 < nkb) {
            const int nb = kbase + 64;
            gl_lds16(Kh + (size_t)(nb + rS) * 64 + cS8,      &smem[(cur ^ 1) * 4096 + tid * 8]);
            gl_lds16(Vh + (size_t)rS * 2048 + nb + cS8,      &smem[8192 + (cur ^ 1) * 4096 + tid * 8]);
        }

        if (kb < nkbw) {
            const unsigned short* KsP = &smem[cur * 4096];
            const unsigned short* VsP = &smem[8192 + cur * 4096];

            const bool fullF = (kbase >= idxb);
            const bool bndF = (!fullF) && (kbase + 63 >= idxb);
            const float zu = fullF ? lw : 0.0f;

            f32x4 sT[4];
            #pragma unroll
            for (int kt = 0; kt < 4; ++kt) {
                const int row = kt * 16 + l15;
                short8 k0 = *(const short8*)&KsP[row * 64 + ((quad ^ (row & 7)) * 8)];
                short8 k1 = *(const short8*)&KsP[row * 64 + (((4 + quad) ^ (row & 7)) * 8)];
                f32x4 z;
                if (!bndF) {
                    z[0] = zu; z[1] = zu; z[2] = zu; z[3] = zu;
                } else {
                    #pragma unroll
                    for (int r = 0; r < 4; ++r)
                        z[r] = (kbase + kt * 16 + quad * 4 + r >= idxb) ? lw : 0.0f;
                }
                z = MFMA_B16(k0, aq0, z);
                z = MFMA_B16(k1, aq1, z);
                sT[kt] = z;
            }

            if (kb == wq) {
                #pragma unroll
                for (int kt = 0; kt < 4; ++kt)
                    #pragma unroll
                    for (int r = 0; r < 4; ++r)
                        if (kbase + kt * 16 + quad * 4 + r > qrow) sT[kt][r] = -3.0e38f;
            }

            #pragma unroll
            for (int kt = 0; kt < 4; ++kt)
                #pragma unroll
                for (int r = 0; r < 4; ++r)
                    sT[kt][r] = EXP2(sT[kt][r]);

            #pragma unroll
            for (int kt = 0; kt < 4; ++kt) {
                unsigned int* pw = (unsigned int*)&pwb[pwr +
                    (((kt * 2 + (quad >> 1)) ^ pa7) * 8) + (quad & 1) * 4];
                pw[0] = pk_bf16(sT[kt][0], sT[kt][1]);
                pw[1] = pk_bf16(sT[kt][2], sT[kt][3]);
            }

            short8 bp0 = *(const short8*)&pwb[pwr + ((quad ^ pa7) * 8)];
            short8 bp1 = *(const short8*)&pwb[pwr + (((4 + quad) ^ pa7) * 8)];

            lsum = MFMA_B16(ones8, bp0, lsum);
            lsum = MFMA_B16(ones8, bp1, lsum);

            #pragma unroll
            for (int dt = 0; dt < 4; ++dt) {
                const int row = dt * 16 + l15;
                short8 vf0 = *(const short8*)&VsP[row * 64 + ((quad ^ (row & 7)) * 8)];
                short8 vf1 = *(const short8*)&VsP[row * 64 + (((4 + quad) ^ (row & 7)) * 8)];
                f32x4 oo = o[dt];
                oo = MFMA_B16(vf0, bp0, oo);
                oo = MFMA_B16(vf1, bp1, oo);
                o[dt] = oo;
            }
        }

        __syncthreads();
    }

    // epilogue: per-wave transpose through LDS scratch (8 waves x 1152 shorts <= 24576)
    const float inv = 1.0f / lsum[0];
    unsigned short* sc = &smem[wave * 1152];
    #pragma unroll
    for (int dt = 0; dt < 4; ++dt)
        #pragma unroll
        for (int r = 0; r < 4; ++r)
            sc[l15 * 72 + dt * 16 + quad * 4 + r] = f2bf(o[dt][r] * inv);
    const size_t rowoff = ((size_t)(b * 2048 + q0 + l15)) * 1024 + hh * 64;
    #pragma unroll
    for (int h = 0; h < 2; ++h) {
        short8 v8 = *(const short8*)&sc[l15 * 72 + quad * 16 + h * 8];
        *(short8*)&O[rowoff + quad * 16 + h * 8] = v8;
    }
}

extern "C" void kernel_launch(void* const* d_in, const int* in_sizes, int n_in,
                              void* d_out, int out_size, void* d_ws, size_t ws_size,
                              hipStream_t stream) {
    const float* x        = (const float*)d_in[0];
    const int*   idx      = (const int*)d_in[1];
    const float* weight   = (const float*)d_in[2];
    const int*   forcing  = (const int*)d_in[3];
    const float* w_qkv    = (const float*)d_in[4];
    const float* b_qkv    = (const float*)d_in[5];
    const float* w_proj   = (const float*)d_in[6];
    const float* b_proj   = (const float*)d_in[7];
    float* out = (float*)d_out;

    char* ws = (char*)d_ws;
    unsigned short* xb      = (unsigned short*)(ws);              // 8 MB (reused: attn_out)
    unsigned short* wqkvT   = (unsigned short*)(ws + 8388608);    // 6 MB
    unsigned short* wprojT  = (unsigned short*)(ws + 14680064);   // 2 MB
    unsigned short* qbuf    = (unsigned short*)(ws + 16777216);   // 8 MB
    unsigned short* kbuf    = (unsigned short*)(ws + 25165824);   // 8 MB
    unsigned short* vTbuf   = (unsigned short*)(ws + 33554432);   // 8 MB
    unsigned short* attn_out = xb;  // xb dead after gemm_qkv

    prep_kernel<<<6144, 256, 0, stream>>>((const float4*)x, (uint4*)xb,
                                          w_qkv, wqkvT, w_proj, wprojT);
    gemm_qkv_kernel<<<192, 512, 0, stream>>>(xb, wqkvT, b_qkv, qbuf, kbuf, vTbuf);
    attn_kernel<<<512, 512, 0, stream>>>(qbuf, kbuf, vTbuf, idx, weight, forcing, attn_out);
    gemm_proj_kernel<<<512, 256, 0, stream>>>(attn_out, wprojT, b_proj, out);
}

// Round 6
// 180.400 us; speedup vs baseline: 1.0474x; 1.0474x over previous
//
#include <hip/hip_runtime.h>

// MultiHeadAttention: B=2,S=2048,D=1024,H=16,dh=64. fp32 in/out, bf16 MFMA internally.
// R13:
//  - gemm_qkv / gemm_proj REVERTED to best-measured R7/R9 forms (128x128 / 128x64 tiles,
//    single-buffer, stage->sync->compute->sync, grids dim3(24,32)/dim3(16,32), 3/CU).
//    R11 dbuf and R12 8-phase both failed to beat it (m99/m232 reproduced).
//  - attn: KVBLK 64 -> 128. Block owns a 128-aligned q-block (rows [128p,128p+128)):
//    waves 0-3 -> upper 64 q, waves 4-7 -> lower 64 q; ALL waves active every k-tile
//    (diagonal idle gone). Halves iterations/barriers/vmcnt-drains at same MFMA work.
//    LDS 80KB: K[2][128x64] | V[2][64x128] | Pw[8][1024] -> exactly 2 blocks/CU.
//    P/PV done as two 64-halves reusing the proven pack/bp/PV code per half.
//    Pairing: bid<256 long (p=8..15), bid>=256 complement (p=7..0), same rem ->
//    CU-paired runtimes sum to 17 tiles; XCD-grouped heads (4 heads/XCD L2).

typedef __attribute__((ext_vector_type(8))) short short8;
typedef __attribute__((ext_vector_type(4))) float f32x4;

#define MFMA_B16(a, b, c) __builtin_amdgcn_mfma_f32_16x16x32_bf16(a, b, c, 0, 0, 0)

#if __has_builtin(__builtin_amdgcn_exp2f)
#define EXP2(x) __builtin_amdgcn_exp2f(x)
#else
#define EXP2(x) exp2f(x)
#endif

static __device__ __forceinline__ unsigned short f2bf(float f) {
    union { float f; unsigned int u; } v;
    v.f = f;
    unsigned int r = (v.u + 0x7fffu + ((v.u >> 16) & 1u)) >> 16;
    return (unsigned short)r;
}

static __device__ __forceinline__ unsigned int pk_bf16(float a, float b) {
#if __has_builtin(__builtin_amdgcn_cvt_pk_bf16_f32)
    typedef __bf16 bf2 __attribute__((ext_vector_type(2)));
    union { bf2 v; unsigned int u; } c;
    c.v = __builtin_amdgcn_cvt_pk_bf16_f32(a, b);
    return c.u;
#else
    return (unsigned int)f2bf(a) | ((unsigned int)f2bf(b) << 16);
#endif
}

static __device__ __forceinline__ void gl_lds16(const void* g, void* l) {
    __builtin_amdgcn_global_load_lds(
        (const __attribute__((address_space(1))) unsigned int*)g,
        (__attribute__((address_space(3))) unsigned int*)l, 16, 0, 0);
}

// ---------------- fused prep: convert x + transpose both weights ----------------
__global__ __launch_bounds__(256) void prep_kernel(const float4* __restrict__ x,
                                                   uint4* __restrict__ xb,
                                                   const float* __restrict__ wqkv,
                                                   unsigned short* __restrict__ wqkvT,
                                                   const float* __restrict__ wproj,
                                                   unsigned short* __restrict__ wprojT) {
    const int bid = blockIdx.x;
    if (bid < 2048) {
        int i = bid * 256 + threadIdx.x;   // 0..524287, 8 floats each
        float4 v0 = x[i * 2], v1 = x[i * 2 + 1];
        uint4 o;
        o.x = pk_bf16(v0.x, v0.y);
        o.y = pk_bf16(v0.z, v0.w);
        o.z = pk_bf16(v1.x, v1.y);
        o.w = pk_bf16(v1.z, v1.w);
        xb[i] = o;
        return;
    }
    __shared__ float t[32][33];
    const float* in;
    unsigned short* out;
    int R, C, bx, by;
    if (bid < 2048 + 3072) {
        int g = bid - 2048;
        in = wqkv; out = wqkvT; R = 1024; C = 3072;
        bx = g % 96; by = g / 96;
    } else {
        int g = bid - 5120;
        in = wproj; out = wprojT; R = 1024; C = 1024;
        bx = g & 31; by = g >> 5;
    }
    const int c0 = bx * 32, r0 = by * 32;
    const int xx = threadIdx.x & 31, yy0 = threadIdx.x >> 5;
    #pragma unroll
    for (int yy = yy0; yy < 32; yy += 8)
        t[yy][xx] = in[(size_t)(r0 + yy) * C + (c0 + xx)];
    __syncthreads();
    #pragma unroll
    for (int yy = yy0; yy < 32; yy += 8)
        out[(size_t)(c0 + yy) * R + (r0 + xx)] = f2bf(t[xx][yy]);
}

// ---------------- QKV GEMM: C[4096x3072] = A * Bt^T (reverted R7 form) ----------------
// blockIdx.x 0..7 = Q (swapped MFMA, scaled), 8..15 = K (swapped), 16..23 = V (unswapped,
// direct b64 stores to vT [bh][d][s]).
__global__ __launch_bounds__(256) void gemm_qkv_kernel(const unsigned short* __restrict__ A,
                                                       const unsigned short* __restrict__ Bt,
                                                       const float* __restrict__ bias,
                                                       unsigned short* __restrict__ q,
                                                       unsigned short* __restrict__ k,
                                                       unsigned short* __restrict__ vT) {
    __shared__ unsigned short As[128 * 64];
    __shared__ unsigned short Bs[128 * 64];
    const int tid = threadIdx.x;
    const int lane = tid & 63, wave = tid >> 6;
    const int l15 = lane & 15, quad = lane >> 4;
    const int wm = wave >> 1, wn = wave & 1;
    const int row0 = blockIdx.y * 128, col0 = blockIdx.x * 128;
    const int K = 1024;
    const bool isV = (blockIdx.x >= 16);

    int srow[4], scol[4], sdst[4];
    #pragma unroll
    for (int h = 0; h < 4; ++h) {
        int D = h * 256 + wave * 64 + lane;
        srow[h] = D >> 3;
        scol[h] = ((D & 7) ^ (srow[h] & 7)) * 8;
        sdst[h] = (h * 256 + wave * 64) * 8;
    }

    f32x4 acc[4][4] = {};

    for (int kt = 0; kt < K; kt += 64) {
        #pragma unroll
        for (int h = 0; h < 4; ++h) {
            gl_lds16(&A[(size_t)(row0 + srow[h]) * K + kt + scol[h]], &As[sdst[h]]);
            gl_lds16(&Bt[(size_t)(col0 + srow[h]) * K + kt + scol[h]], &Bs[sdst[h]]);
        }
        __syncthreads();
        #pragma unroll
        for (int kk = 0; kk < 2; ++kk) {
            short8 af[4], bf[4];
            #pragma unroll
            for (int i = 0; i < 4; ++i) {
                int r = wm * 64 + i * 16 + l15;
                af[i] = *(const short8*)&As[r * 64 + (((kk * 4 + quad) ^ (r & 7)) * 8)];
            }
            #pragma unroll
            for (int j = 0; j < 4; ++j) {
                int r = wn * 64 + j * 16 + l15;
                bf[j] = *(const short8*)&Bs[r * 64 + (((kk * 4 + quad) ^ (r & 7)) * 8)];
            }
            if (isV) {
                #pragma unroll
                for (int i = 0; i < 4; ++i)
                    #pragma unroll
                    for (int j = 0; j < 4; ++j)
                        acc[i][j] = MFMA_B16(af[i], bf[j], acc[i][j]);  // C
            } else {
                #pragma unroll
                for (int i = 0; i < 4; ++i)
                    #pragma unroll
                    for (int j = 0; j < 4; ++j)
                        acc[i][j] = MFMA_B16(bf[j], af[i], acc[i][j]);  // C^T
            }
        }
        __syncthreads();
    }

    const int b = row0 >> 11;
    const int s0 = row0 & 2047;
    const float* bb = bias + col0 + wn * 64;

    if (!isV) {
        // C^T: lane holds d = j*16 + quad*4 + {0..3} for s = wm*64 + i*16 + l15
        const int which = blockIdx.x >> 3;  // 0=Q, 1=K
        unsigned short* dst = which ? k : q;
        const float scale = which ? 1.0f : 0.1803368867f;  // 1/8 * log2(e) for Q
        const int hh = ((blockIdx.x & 7) << 1) + wn;
        #pragma unroll
        for (int i = 0; i < 4; ++i) {
            const int s = s0 + wm * 64 + i * 16 + l15;
            unsigned short* drow = dst + ((size_t)((b * 16 + hh) * 2048 + s)) * 64;
            #pragma unroll
            for (int j = 0; j < 4; ++j) {
                float4 b4 = ((const float4*)bb)[j * 4 + quad];
                uint2 pv;
                pv.x = pk_bf16((acc[i][j][0] + b4.x) * scale, (acc[i][j][1] + b4.y) * scale);
                pv.y = pk_bf16((acc[i][j][2] + b4.z) * scale, (acc[i][j][3] + b4.w) * scale);
                *(uint2*)&drow[j * 16 + quad * 4] = pv;
            }
        }
    } else {
        // C: lane holds s = wm*64 + i*16 + quad*4 + {0..3} for d = j*16 + l15
        const int hh = ((blockIdx.x - 16) << 1) + wn;
        #pragma unroll
        for (int j = 0; j < 4; ++j) {
            const int d = j * 16 + l15;
            const float bv = bb[d];
            unsigned short* drow = vT + ((size_t)((b * 16 + hh) * 64 + d)) * 2048 + s0;
            #pragma unroll
            for (int i = 0; i < 4; ++i) {
                uint2 pv;
                pv.x = pk_bf16(acc[i][j][0] + bv, acc[i][j][1] + bv);
                pv.y = pk_bf16(acc[i][j][2] + bv, acc[i][j][3] + bv);
                *(uint2*)&drow[wm * 64 + i * 16 + quad * 4] = pv;
            }
        }
    }
}

// ---------------- proj GEMM: out[4096x1024] fp32 = A * Bt^T + bias (reverted R7) -------
__global__ __launch_bounds__(256) void gemm_proj_kernel(const unsigned short* __restrict__ A,
                                                        const unsigned short* __restrict__ Bt,
                                                        const float* __restrict__ bias,
                                                        float* __restrict__ out) {
    __shared__ unsigned short As[128 * 64];
    __shared__ unsigned short Bs[64 * 64];
    const int tid = threadIdx.x;
    const int lane = tid & 63, wave = tid >> 6;
    const int l15 = lane & 15, quad = lane >> 4;
    const int wm = wave >> 1, wn = wave & 1;
    const int row0 = blockIdx.y * 128, col0 = blockIdx.x * 64;
    const int K = 1024;

    int srow[4], scol[4], sdst[4];
    #pragma unroll
    for (int h = 0; h < 4; ++h) {
        int D = h * 256 + wave * 64 + lane;
        srow[h] = D >> 3;
        scol[h] = ((D & 7) ^ (srow[h] & 7)) * 8;
        sdst[h] = (h * 256 + wave * 64) * 8;
    }

    f32x4 acc[4][2] = {};

    for (int kt = 0; kt < K; kt += 64) {
        #pragma unroll
        for (int h = 0; h < 4; ++h)
            gl_lds16(&A[(size_t)(row0 + srow[h]) * K + kt + scol[h]], &As[sdst[h]]);
        #pragma unroll
        for (int h = 0; h < 2; ++h)
            gl_lds16(&Bt[(size_t)(col0 + srow[h]) * K + kt + scol[h]], &Bs[sdst[h]]);
        __syncthreads();
        #pragma unroll
        for (int kk = 0; kk < 2; ++kk) {
            short8 af[4], bf[2];
            #pragma unroll
            for (int i = 0; i < 4; ++i) {
                int r = wm * 64 + i * 16 + l15;
                af[i] = *(const short8*)&As[r * 64 + (((kk * 4 + quad) ^ (r & 7)) * 8)];
            }
            #pragma unroll
            for (int j = 0; j < 2; ++j) {
                int r = wn * 32 + j * 16 + l15;
                bf[j] = *(const short8*)&Bs[r * 64 + (((kk * 4 + quad) ^ (r & 7)) * 8)];
            }
            #pragma unroll
            for (int i = 0; i < 4; ++i)
                #pragma unroll
                for (int j = 0; j < 2; ++j)
                    acc[i][j] = MFMA_B16(bf[j], af[i], acc[i][j]);  // C^T
        }
        __syncthreads();
    }

    const float* bb = bias + col0 + wn * 32;
    #pragma unroll
    for (int i = 0; i < 4; ++i) {
        const int row = row0 + wm * 64 + i * 16 + l15;
        #pragma unroll
        for (int j = 0; j < 2; ++j) {
            float4 b4 = ((const float4*)bb)[j * 4 + quad];
            float4 ov;
            ov.x = acc[i][j][0] + b4.x;
            ov.y = acc[i][j][1] + b4.y;
            ov.z = acc[i][j][2] + b4.z;
            ov.w = acc[i][j][3] + b4.w;
            *(float4*)&out[(size_t)row * 1024 + col0 + wn * 32 + j * 16 + quad * 4] = ov;
        }
    }
}

// ---------------- flash attention (R13: KVBLK=128, all-wave-active blocks) -------------
// smem (shorts): [0..16383] Ks[2][2 halves][64x64] | [16384..32767] Vs[2][2][64x64]
//                | [32768..40959] Pw[8][1024].  Total 80KB -> 2 blocks/CU.
__global__ __launch_bounds__(512) void attn_kernel(const unsigned short* __restrict__ Q,
                                                   const unsigned short* __restrict__ Kg,
                                                   const unsigned short* __restrict__ Vt,
                                                   const int* __restrict__ idx,
                                                   const float* __restrict__ weight,
                                                   const int* __restrict__ forcing,
                                                   unsigned short* __restrict__ O) {
    __shared__ unsigned short smem[40960];

    const int tid = threadIdx.x;
    const int lane = tid & 63, wave = tid >> 6;
    const int l15 = lane & 15, quad = lane >> 4;
    const int bid = blockIdx.x;
    // bid<256 = long blocks (p=8..15), bid>=256 = complements (p=7..0) with the same
    // rem -> CU-paired blocks run (p+1)+(16-p) = 17 tiles total and share the same
    // head's K/V stream. rem&7 ~ XCD -> 4 heads per XCD (2MB K/V in its L2).
    const int qh = bid >> 8;
    const int rem = bid & 255;
    const int xcd = rem & 7;
    const int head = (rem >> 3) & 3;
    const int g2 = rem >> 5;          // 0..7
    const int p = qh ? (7 - g2) : (8 + g2);
    const int bh = xcd * 4 + head;
    const int b = bh >> 4, hh = bh & 15;
    const unsigned short* Qb = Q + (size_t)bh * 2048 * 64;
    const unsigned short* Kh = Kg + (size_t)bh * 2048 * 64;
    const unsigned short* Vh = Vt + (size_t)bh * 2048 * 64;

    const int idxb = idx[b];
    const float lw = (forcing[0] != 0) ? __log2f(weight[0]) : 0.0f;

    // q-block rows [128p, 128p+128): waves 0-3 -> upper 64, waves 4-7 -> lower 64.
    const int wq = 2 * p + ((wave < 4) ? 1 : 0);
    const int wg = wave & 3;
    const int q0 = wq * 64 + wg * 16;
    const int qrow = q0 + l15;
    const int nkb = p + 1;            // 128-wide k-tiles

    // staging: 512 threads, 4 x 16B per tile (K half0/half1, V half0/half1)
    const int rS = tid >> 3;
    const int cS8 = ((tid & 7) ^ (rS & 7)) * 8;

    short8 aq0 = *(const short8*)&Qb[(q0 + l15) * 64 + quad * 8];
    short8 aq1 = *(const short8*)&Qb[(q0 + l15) * 64 + 32 + quad * 8];

    const short8 ones8 = {0x3F80, 0x3F80, 0x3F80, 0x3F80, 0x3F80, 0x3F80, 0x3F80, 0x3F80};

    f32x4 o[4] = {};
    f32x4 lsum = {};

    // prologue: stage tile 0
    gl_lds16(Kh + (size_t)rS * 64 + cS8,             &smem[tid * 8]);
    gl_lds16(Kh + (size_t)(64 + rS) * 64 + cS8,      &smem[4096 + tid * 8]);
    gl_lds16(Vh + (size_t)rS * 2048 + cS8,           &smem[16384 + tid * 8]);
    gl_lds16(Vh + (size_t)rS * 2048 + 64 + cS8,      &smem[16384 + 4096 + tid * 8]);
    __syncthreads();

    unsigned short* const pwb = &smem[32768 + wave * 1024];
    const int pwr = l15 * 64;
    const int pa7 = l15 & 7;

    for (int kb = 0; kb < nkb; ++kb) {
        const int cur = kb & 1;
        const int kbase = kb * 128;
        if (kb + 1 < nkb) {
            const int nb = kbase + 128;
            gl_lds16(Kh + (size_t)(nb + rS) * 64 + cS8,      &smem[(cur ^ 1) * 8192 + tid * 8]);
            gl_lds16(Kh + (size_t)(nb + 64 + rS) * 64 + cS8, &smem[(cur ^ 1) * 8192 + 4096 + tid * 8]);
            gl_lds16(Vh + (size_t)rS * 2048 + nb + cS8,      &smem[16384 + (cur ^ 1) * 8192 + tid * 8]);
            gl_lds16(Vh + (size_t)rS * 2048 + nb + 64 + cS8, &smem[16384 + (cur ^ 1) * 8192 + 4096 + tid * 8]);
        }

        const unsigned short* KsP = &smem[cur * 8192];
        const unsigned short* VsP = &smem[16384 + cur * 8192];

        const bool fullF = (kbase >= idxb);
        const bool bndF = (!fullF) && (kbase + 127 >= idxb);
        const float zu = fullF ? lw : 0.0f;

        // QK^T over the full 128-wide tile (two 64-halves of K)
        f32x4 sT[8];
        #pragma unroll
        for (int kt = 0; kt < 8; ++kt) {
            const int lr = (kt & 3) * 16 + l15;
            const unsigned short* Kp = KsP + (kt >> 2) * 4096;
            short8 k0 = *(const short8*)&Kp[lr * 64 + ((quad ^ (lr & 7)) * 8)];
            short8 k1 = *(const short8*)&Kp[lr * 64 + (((4 + quad) ^ (lr & 7)) * 8)];
            f32x4 z;
            if (!bndF) {
                z[0] = zu; z[1] = zu; z[2] = zu; z[3] = zu;
            } else {
                #pragma unroll
                for (int r = 0; r < 4; ++r)
                    z[r] = (kbase + kt * 16 + quad * 4 + r >= idxb) ? lw : 0.0f;
            }
            z = MFMA_B16(k0, aq0, z);
            z = MFMA_B16(k1, aq1, z);
            sT[kt] = z;
        }

        if (kb == nkb - 1) {   // diagonal 128-tile (covers both wave-groups' masking)
            #pragma unroll
            for (int kt = 0; kt < 8; ++kt)
                #pragma unroll
                for (int r = 0; r < 4; ++r)
                    if (kbase + kt * 16 + quad * 4 + r > qrow) sT[kt][r] = -3.0e38f;
        }

        #pragma unroll
        for (int kt = 0; kt < 8; ++kt)
            #pragma unroll
            for (int r = 0; r < 4; ++r)
                sT[kt][r] = EXP2(sT[kt][r]);

        // P pack + lsum + PV, one 64-half at a time (reuses 1KB pwb per wave)
        #pragma unroll
        for (int h = 0; h < 2; ++h) {
            #pragma unroll
            for (int kt = 0; kt < 4; ++kt) {
                f32x4 s = sT[h * 4 + kt];
                unsigned int* pw = (unsigned int*)&pwb[pwr +
                    (((kt * 2 + (quad >> 1)) ^ pa7) * 8) + (quad & 1) * 4];
                pw[0] = pk_bf16(s[0], s[1]);
                pw[1] = pk_bf16(s[2], s[3]);
            }

            short8 bp0 = *(const short8*)&pwb[pwr + ((quad ^ pa7) * 8)];
            short8 bp1 = *(const short8*)&pwb[pwr + (((4 + quad) ^ pa7) * 8)];

            lsum = MFMA_B16(ones8, bp0, lsum);
            lsum = MFMA_B16(ones8, bp1, lsum);

            const unsigned short* Vp = VsP + h * 4096;
            #pragma unroll
            for (int dt = 0; dt < 4; ++dt) {
                const int row = dt * 16 + l15;
                short8 vf0 = *(const short8*)&Vp[row * 64 + ((quad ^ (row & 7)) * 8)];
                short8 vf1 = *(const short8*)&Vp[row * 64 + (((4 + quad) ^ (row & 7)) * 8)];
                f32x4 oo = o[dt];
                oo = MFMA_B16(vf0, bp0, oo);
                oo = MFMA_B16(vf1, bp1, oo);
                o[dt] = oo;
            }
        }

        __syncthreads();
    }

    // epilogue: per-wave transpose through LDS scratch (8 waves x 1152 shorts, disjoint)
    const float inv = 1.0f / lsum[0];
    unsigned short* sc = &smem[wave * 1152];
    #pragma unroll
    for (int dt = 0; dt < 4; ++dt)
        #pragma unroll
        for (int r = 0; r < 4; ++r)
            sc[l15 * 72 + dt * 16 + quad * 4 + r] = f2bf(o[dt][r] * inv);
    const size_t rowoff = ((size_t)(b * 2048 + q0 + l15)) * 1024 + hh * 64;
    #pragma unroll
    for (int h = 0; h < 2; ++h) {
        short8 v8 = *(const short8*)&sc[l15 * 72 + quad * 16 + h * 8];
        *(short8*)&O[rowoff + quad * 16 + h * 8] = v8;
    }
}

extern "C" void kernel_launch(void* const* d_in, const int* in_sizes, int n_in,
                              void* d_out, int out_size, void* d_ws, size_t ws_size,
                              hipStream_t stream) {
    const float* x        = (const float*)d_in[0];
    const int*   idx      = (const int*)d_in[1];
    const float* weight   = (const float*)d_in[2];
    const int*   forcing  = (const int*)d_in[3];
    const float* w_qkv    = (const float*)d_in[4];
    const float* b_qkv    = (const float*)d_in[5];
    const float* w_proj   = (const float*)d_in[6];
    const float* b_proj   = (const float*)d_in[7];
    float* out = (float*)d_out;

    char* ws = (char*)d_ws;
    unsigned short* xb      = (unsigned short*)(ws);              // 8 MB (reused: attn_out)
    unsigned short* wqkvT   = (unsigned short*)(ws + 8388608);    // 6 MB
    unsigned short* wprojT  = (unsigned short*)(ws + 14680064);   // 2 MB
    unsigned short* qbuf    = (unsigned short*)(ws + 16777216);   // 8 MB
    unsigned short* kbuf    = (unsigned short*)(ws + 25165824);   // 8 MB
    unsigned short* vTbuf   = (unsigned short*)(ws + 33554432);   // 8 MB
    unsigned short* attn_out = xb;  // xb dead after gemm_qkv

    prep_kernel<<<6144, 256, 0, stream>>>((const float4*)x, (uint4*)xb,
                                          w_qkv, wqkvT, w_proj, wprojT);
    gemm_qkv_kernel<<<dim3(24, 32), 256, 0, stream>>>(xb, wqkvT, b_qkv, qbuf, kbuf, vTbuf);
    attn_kernel<<<512, 512, 0, stream>>>(qbuf, kbuf, vTbuf, idx, weight, forcing, attn_out);
    gemm_proj_kernel<<<dim3(16, 32), 256, 0, stream>>>(attn_out, wprojT, b_proj, out);
}